// Round 8
// baseline (566.517 us; speedup 1.0000x reference)
//
#include <hip/hip_runtime.h>
#include <hip/hip_fp16.h>
#include <cstdint>

#define NNODES 50000

__device__ inline void wave_lds_fence() {
  asm volatile("s_waitcnt lgkmcnt(0)" ::: "memory");
  __builtin_amdgcn_wave_barrier();
}

// ---------------- CSR build (dst-major, self-loops appended) ----------------
__global__ void hist_kernel(const int* __restrict__ ei, int E, int Nn, int* __restrict__ cnt) {
  int i = blockIdx.x * blockDim.x + threadIdx.x;
  int ET = E + Nn;
  if (i >= ET) return;
  int d = (i < E) ? ei[E + i] : (i - E);
  atomicAdd(&cnt[d], 1);
}

__global__ void scan1_kernel(const int* __restrict__ in, int n, int* __restrict__ incl,
                             int* __restrict__ bsum) {
  __shared__ int sd[256];
  int g = blockIdx.x * 256 + threadIdx.x;
  int v = (g < n) ? in[g] : 0;
  sd[threadIdx.x] = v;
  __syncthreads();
  for (int off = 1; off < 256; off <<= 1) {
    int t = (threadIdx.x >= off) ? sd[threadIdx.x - off] : 0;
    __syncthreads();
    sd[threadIdx.x] += t;
    __syncthreads();
  }
  if (g < n) incl[g] = sd[threadIdx.x];
  if (threadIdx.x == 255) bsum[blockIdx.x] = sd[255];
}

__global__ void scan3_kernel(const int* __restrict__ incl, const int* __restrict__ bscan,
                             int n, int* __restrict__ rowptr) {
  int g = blockIdx.x * 256 + threadIdx.x;
  if (g == 0) rowptr[0] = 0;
  if (g < n) {
    int off = (blockIdx.x > 0) ? bscan[blockIdx.x - 1] : 0;
    rowptr[g + 1] = incl[g] + off;
  }
}

__global__ void scatter_kernel(const int* __restrict__ ei, int E, int Nn,
                               const int* __restrict__ rowptr, int* __restrict__ cnt2,
                               int* __restrict__ esorted) {
  int i = blockIdx.x * blockDim.x + threadIdx.x;
  int ET = E + Nn;
  if (i >= ET) return;
  int s, d;
  if (i < E) { s = ei[i]; d = ei[E + i]; }
  else       { s = i - E; d = i - E; }
  int pos = rowptr[d] + atomicAdd(&cnt2[d], 1);
  esorted[pos] = s;
}

// ---------------- GEMM + fused attention logits (LDS-tiled W, double-buffered) -------------
// Hout[N,HCP](fp16, row stride HCP) = X[N,FIN](fp32) @ W[FIN,HC](fp32)
// W is staged to LDS in KT=16-row tiles, double-buffered: per tile, {global->reg
// loads issued BEFORE the FMA block (latency hides under 256 FMAs), reg->LDS write
// after, one __syncthreads per tile}. This cuts the per-WAVE W re-stream from L2
// (R7: ~1.1 GB L2 traffic for L3) to per-BLOCK (~0.3 GB total) and replaces
// latency-fragile global loads in the inner loop with ds_read_b128.
// Logit reduction is ATOMIC-FREE (distinct LDS cells, R7-verified).
template <int FIN, int H, int C, int HCP, int BLOCK>
__global__ __launch_bounds__(BLOCK) void gemm_alpha_kernel(const float* __restrict__ X,
                                                           const float* __restrict__ W,
                                                           const float* __restrict__ a_s,
                                                           const float* __restrict__ a_d,
                                                           __half* __restrict__ Hout,
                                                           float* __restrict__ als8,
                                                           float* __restrict__ ald8) {
  constexpr int HC = H * C;
  constexpr int NT = 16;
  constexpr int TM = 4, TN = 4;
  constexpr int CG = HC / TN;
  constexpr int MAXC = C / TN;              // 4-col slices per head
  constexpr int KT = 16;                    // W rows per LDS tile
  constexpr int NTILE = FIN / KT;           // 8 / 7 / 6
  constexpr int WTILE = KT * HC;            // floats per tile (1792 / 1536 / 3840)
  constexpr int LPT = (WTILE + BLOCK * 4 - 1) / (BLOCK * 4);  // float4 loads/thread/tile
  static_assert(FIN % KT == 0, "FIN must be a multiple of KT");
  static_assert(WTILE % 4 == 0, "W tile must be float4-aligned");
  __shared__ __align__(16) float xs[FIN * NT];   // [k][node]
  __shared__ __align__(16) float ws[2][WTILE];   // double-buffered W tile [k][c]
  __shared__ float redS[NT][H][MAXC];
  __shared__ float redD[NT][H][MAXC];
  const int n0 = blockIdx.x * NT;

  // stage X block (16 nodes) transposed into xs
  for (int i = threadIdx.x * 4; i < NT * FIN; i += BLOCK * 4) {
    float4 v = *(const float4*)(X + (size_t)n0 * FIN + i);
    int node = i / FIN, k = i % FIN;
    xs[(k + 0) * NT + node] = v.x;
    xs[(k + 1) * NT + node] = v.y;
    xs[(k + 2) * NT + node] = v.z;
    xs[(k + 3) * NT + node] = v.w;
  }

  // W tile staging helpers (tile kt = contiguous WTILE floats at W + kt*WTILE)
  float4 wr[LPT];
  auto load_tile = [&](int kt) {
    const float* src = W + (size_t)kt * WTILE;
#pragma unroll
    for (int i = 0; i < LPT; ++i) {
      int p = (i * BLOCK + threadIdx.x) * 4;
      if (p < WTILE) wr[i] = *(const float4*)(src + p);
    }
  };
  auto write_tile = [&](int buf) {
#pragma unroll
    for (int i = 0; i < LPT; ++i) {
      int p = (i * BLOCK + threadIdx.x) * 4;
      if (p < WTILE) *(float4*)(&ws[buf][p]) = wr[i];
    }
  };

  load_tile(0);
  write_tile(0);
  __syncthreads();  // xs + ws[0] ready

  const int cg = threadIdx.x % CG;
  const int ng = threadIdx.x / CG;
  const bool compute = (ng < NT / TM);
  const int c0 = cg * TN;
  const int i0 = ng * TM;
  float acc[TM][TN];
#pragma unroll
  for (int i = 0; i < TM; ++i)
#pragma unroll
    for (int j = 0; j < TN; ++j) acc[i][j] = 0.f;

  int cur = 0;
#pragma unroll 1
  for (int kt = 0; kt < NTILE; ++kt) {
    if (kt + 1 < NTILE) load_tile(kt + 1);  // global->reg, lands during FMA below
    if (compute) {
      const float* wp = &ws[cur][0] + c0;
#pragma unroll
      for (int k = 0; k < KT; ++k) {
        const float4 wv = *(const float4*)(wp + k * HC);
        const float4 xv = *(const float4*)(xs + (kt * KT + k) * NT + i0);
        acc[0][0] += xv.x * wv.x; acc[0][1] += xv.x * wv.y; acc[0][2] += xv.x * wv.z; acc[0][3] += xv.x * wv.w;
        acc[1][0] += xv.y * wv.x; acc[1][1] += xv.y * wv.y; acc[1][2] += xv.y * wv.z; acc[1][3] += xv.y * wv.w;
        acc[2][0] += xv.z * wv.x; acc[2][1] += xv.z * wv.y; acc[2][2] += xv.z * wv.z; acc[2][3] += xv.z * wv.w;
        acc[3][0] += xv.w * wv.x; acc[3][1] += xv.w * wv.y; acc[3][2] += xv.w * wv.z; acc[3][3] += xv.w * wv.w;
      }
    }
    if (kt + 1 < NTILE) write_tile(cur ^ 1);  // safe: ws[cur^1] last read in tile kt-1
    __syncthreads();
    cur ^= 1;
  }

  if (compute) {
    // store h (fp16, padded stride)
#pragma unroll
    for (int i = 0; i < TM; ++i) {
      union { __half2 h2[2]; uint2 u; } pk;
      pk.h2[0] = __floats2half2_rn(acc[i][0], acc[i][1]);
      pk.h2[1] = __floats2half2_rn(acc[i][2], acc[i][3]);
      *(uint2*)(Hout + (size_t)(n0 + i0 + i) * HCP + c0) = pk.u;
    }
    // logit partials: this thread's 4 cols all lie in head hd, slice cidx
    const int hd = c0 / C;
    const int cidx = (c0 % C) / TN;
    const float4 as4 = *(const float4*)(a_s + c0);
    const float4 ad4 = *(const float4*)(a_d + c0);
#pragma unroll
    for (int i = 0; i < TM; ++i) {
      float ps = acc[i][0] * as4.x + acc[i][1] * as4.y + acc[i][2] * as4.z + acc[i][3] * as4.w;
      float pd = acc[i][0] * ad4.x + acc[i][1] * ad4.y + acc[i][2] * ad4.z + acc[i][3] * ad4.w;
      redS[i0 + i][hd][cidx] = ps;
      redD[i0 + i][hd][cidx] = pd;
    }
  }
  __syncthreads();
  for (int z = threadIdx.x; z < NT * H; z += BLOCK) {
    int n = z / H, h = z % H;
    float ss = 0.f, dd = 0.f;
#pragma unroll
    for (int c = 0; c < MAXC; ++c) { ss += redS[n][h][c]; dd += redD[n][h][c]; }
    als8[(size_t)(n0 + n) * 8 + h] = ss;
    ald8[(size_t)(n0 + n) * 8 + h] = dd;
  }
}

// ---------------- segment softmax + aggregate (one wave per dst node) ----------------
// No max-subtraction: scores are O(+-5) for this data scale, exp() is safe in fp32
// and alpha = exp(e)/sum exp(e) is mathematically identical to the max-shifted form.
//
// Gather layout: each lane owns one 16-B chunk (8 halves) of the src feature
// vector; 64 lanes = GROUPS edge-parallel groups x LPG chunk-lanes. Rows are
// HCP-padded so each per-edge gather covers exactly HCP*2/128 aligned lines.
template <int H, int C, int HCP, int RELU>
__global__ __launch_bounds__(256) void agg_kernel(const __half* __restrict__ Hbuf,
                                                  const float* __restrict__ als8,
                                                  const float* __restrict__ ald8,
                                                  const int* __restrict__ rowptr,
                                                  const int* __restrict__ esrc,
                                                  const float* __restrict__ bias,
                                                  float* __restrict__ Out, int n_nodes) {
  constexpr int HC = H * C;
  constexpr int NCHUNK = HC / 8;                    // real 16-B chunks per feature vector
  constexpr int GROUPS = (NCHUNK <= 16) ? 4 : 2;    // edge-parallel groups per wave
  constexpr int LPG = 64 / GROUPS;                  // chunk-lanes per group
  constexpr int UN = 3;                             // edges in flight per group (MLP)
  constexpr int TPAD = 72;                          // 64 staged + group-stride overshoot pad
  const int wave = threadIdx.x >> 6;
  const int lane = threadIdx.x & 63;
  const int grp = lane / LPG;
  const int lg = lane % LPG;
  const int n = blockIdx.x * 4 + wave;
  __shared__ float s_w[4][TPAD * H];  // per-edge softmax weights for current chunk
  __shared__ int s_src[4][TPAD];
  if (n >= n_nodes) return;

  // zero the overshoot pad once (weight 0 => padded slots contribute nothing)
  if (lane < TPAD - 64) s_src[wave][64 + lane] = 0;
  for (int z = lane; z < (TPAD - 64) * H; z += 64) s_w[wave][64 * H + z] = 0.f;

  const int e0 = rowptr[n];
  const int e1 = rowptr[n + 1];

  float aldn[H];
#pragma unroll
  for (int h = 0; h < H; ++h) aldn[h] = ald8[n * 8 + h];

  // lane's chunk lies in exactly one head since C % 8 == 0 (C = 16 or 40)
  const int head = min((lg * 8) / C, H - 1);
  const bool act = lg < NCHUNK;

  float acc[8];
  float lsum = 0.f;
#pragma unroll
  for (int j = 0; j < 8; ++j) acc[j] = 0.f;

  for (int base = e0; base < e1; base += 64) {
    const int cnt = (e1 - base < 64) ? (e1 - base) : 64;
    int sreg = 0;
    if (lane < cnt) sreg = esrc[base + lane];
    s_src[wave][lane] = sreg;  // lanes >= cnt stage src 0 with weight 0 (harmless pad)
    if (lane < cnt) {
      const float4 qa = *(const float4*)(als8 + (size_t)sreg * 8);
      const float4 qb = *(const float4*)(als8 + (size_t)sreg * 8 + 4);
      const float q[8] = {qa.x, qa.y, qa.z, qa.w, qb.x, qb.y, qb.z, qb.w};
#pragma unroll
      for (int h = 0; h < H; ++h) {
        float v = q[h] + aldn[h];
        v = v > 0.f ? v : 0.2f * v;  // leaky_relu 0.2
        s_w[wave][lane * H + h] = __expf(v);
      }
    } else {
#pragma unroll
      for (int h = 0; h < H; ++h) s_w[wave][lane * H + h] = 0.f;
    }
    wave_lds_fence();
    // each group sweeps edges t = grp, grp+GROUPS, ...; UN edges per group in flight
    const int nit = (cnt + GROUPS - 1) / GROUPS;
    for (int i = 0; i < nit; i += UN) {
      int tt[UN], si[UN];
      uint4 v[UN];
      float w[UN];
#pragma unroll
      for (int k = 0; k < UN; ++k) tt[k] = (i + k) * GROUPS + grp;
#pragma unroll
      for (int k = 0; k < UN; ++k) si[k] = s_src[wave][tt[k]];
#pragma unroll
      for (int k = 0; k < UN; ++k)
        if (act) v[k] = *(const uint4*)(Hbuf + (size_t)si[k] * HCP + lg * 8);
#pragma unroll
      for (int k = 0; k < UN; ++k) w[k] = s_w[wave][tt[k] * H + head];
#pragma unroll
      for (int k = 0; k < UN; ++k)
        if (act) {
          const __half2* hp = (const __half2*)&v[k];
          float2 f0 = __half22float2(hp[0]);
          float2 f1 = __half22float2(hp[1]);
          float2 f2 = __half22float2(hp[2]);
          float2 f3 = __half22float2(hp[3]);
          lsum += w[k];
          acc[0] += w[k] * f0.x; acc[1] += w[k] * f0.y;
          acc[2] += w[k] * f1.x; acc[3] += w[k] * f1.y;
          acc[4] += w[k] * f2.x; acc[5] += w[k] * f2.y;
          acc[6] += w[k] * f3.x; acc[7] += w[k] * f3.y;
        }
    }
    wave_lds_fence();
  }

  // fold group partials: lanes with equal lg hold the same channels
#pragma unroll
  for (int off = LPG; off < 64; off <<= 1) {
    lsum += __shfl_xor(lsum, off);
#pragma unroll
    for (int j = 0; j < 8; ++j) acc[j] += __shfl_xor(acc[j], off);
  }

  if (grp == 0 && act) {
    const float inv = 1.f / lsum;
    const float4 b0 = *(const float4*)(bias + lg * 8);
    const float4 b1 = *(const float4*)(bias + lg * 8 + 4);
    float4 o0, o1;
    o0.x = acc[0] * inv + b0.x; o0.y = acc[1] * inv + b0.y;
    o0.z = acc[2] * inv + b0.z; o0.w = acc[3] * inv + b0.w;
    o1.x = acc[4] * inv + b1.x; o1.y = acc[5] * inv + b1.y;
    o1.z = acc[6] * inv + b1.z; o1.w = acc[7] * inv + b1.w;
    if (RELU) {
      o0.x = fmaxf(o0.x, 0.f); o0.y = fmaxf(o0.y, 0.f);
      o0.z = fmaxf(o0.z, 0.f); o0.w = fmaxf(o0.w, 0.f);
      o1.x = fmaxf(o1.x, 0.f); o1.y = fmaxf(o1.y, 0.f);
      o1.z = fmaxf(o1.z, 0.f); o1.w = fmaxf(o1.w, 0.f);
    }
    *(float4*)(Out + (size_t)n * HC + lg * 8) = o0;
    *(float4*)(Out + (size_t)n * HC + lg * 8 + 4) = o1;
  }
}

// ---------------- launch ----------------
extern "C" void kernel_launch(void* const* d_in, const int* in_sizes, int n_in,
                              void* d_out, int out_size, void* d_ws, size_t ws_size,
                              hipStream_t stream) {
  const int N = NNODES;
  const float* x  = (const float*)d_in[0];
  const int* ei   = (const int*)d_in[1];
  const float* W1 = (const float*)d_in[2];
  const float* as1 = (const float*)d_in[3];
  const float* ad1 = (const float*)d_in[4];
  const float* b1  = (const float*)d_in[5];
  const float* W2  = (const float*)d_in[6];
  const float* as2 = (const float*)d_in[7];
  const float* ad2 = (const float*)d_in[8];
  const float* b2  = (const float*)d_in[9];
  const float* W3  = (const float*)d_in[10];
  const float* as3 = (const float*)d_in[11];
  const float* ad3 = (const float*)d_in[12];
  const float* b3  = (const float*)d_in[13];
  float* out = (float*)d_out;
  const int E = in_sizes[1] / 2;
  const int ET = E + N;

  char* ws = (char*)d_ws;
  size_t off = 0;
  auto alloc = [&](size_t bytes) -> char* {
    char* p = ws + off;
    off += (bytes + 255) & ~(size_t)255;
    return p;
  };
  int* cnt     = (int*)alloc((size_t)N * 4);
  int* cnt2    = (int*)alloc((size_t)N * 4);
  int* incl    = (int*)alloc((size_t)N * 4);
  int* bsum    = (int*)alloc(512 * 4);
  int* bscan   = (int*)alloc(256 * 4);
  int* rowptr  = (int*)alloc((size_t)(N + 1) * 4);
  int* esorted = (int*)alloc((size_t)ET * 4);
  float* als   = (float*)alloc((size_t)N * 8 * 4);
  float* ald   = (float*)alloc((size_t)N * 8 * 4);
  __half* hbuf = (__half*)alloc((size_t)N * 256 * 2);  // max padded row stride = 256 halves
  float* abuf  = (float*)alloc((size_t)N * 112 * 4);

  hipMemsetAsync(cnt, 0, (size_t)N * 4, stream);
  hipMemsetAsync(cnt2, 0, (size_t)N * 4, stream);

  const int B1 = (N + 255) / 256;
  hist_kernel<<<(ET + 255) / 256, 256, 0, stream>>>(ei, E, N, cnt);
  scan1_kernel<<<B1, 256, 0, stream>>>(cnt, N, incl, bsum);
  scan1_kernel<<<1, 256, 0, stream>>>(bsum, B1, bscan, bsum + 256);
  scan3_kernel<<<B1, 256, 0, stream>>>(incl, bscan, N, rowptr);
  scatter_kernel<<<(ET + 255) / 256, 256, 0, stream>>>(ei, E, N, rowptr, cnt2, esorted);

  // Layer 1: 128 -> 7x16, rows padded 112 -> 128 halves (256 B = 2 aligned lines/gather)
  gemm_alpha_kernel<128, 7, 16, 128, 128><<<N / 16, 128, 0, stream>>>(x, W1, as1, ad1, hbuf, als, ald);
  agg_kernel<7, 16, 128, 1><<<(N + 3) / 4, 256, 0, stream>>>(hbuf, als, ald, rowptr, esorted, b1, abuf, N);
  // Layer 2: 112 -> 6x16, stride 96 halves (192 B) already always 2 lines -> unpadded
  gemm_alpha_kernel<112, 6, 16, 96, 128><<<N / 16, 128, 0, stream>>>(abuf, W2, as2, ad2, hbuf, als, ald);
  agg_kernel<6, 16, 96, 1><<<(N + 3) / 4, 256, 0, stream>>>(hbuf, als, ald, rowptr, esorted, b2, abuf, N);
  // Layer 3: 96 -> 6x40 (no relu), rows padded 240 -> 256 halves (512 B = 4 aligned lines)
  gemm_alpha_kernel<96, 6, 40, 256, 256><<<N / 16, 256, 0, stream>>>(abuf, W3, as3, ad3, hbuf, als, ald);
  agg_kernel<6, 40, 256, 0><<<(N + 3) / 4, 256, 0, stream>>>(hbuf, als, ald, rowptr, esorted, b3, out, N);
}

// Round 9
// 455.869 us; speedup vs baseline: 1.2427x; 1.2427x over previous
//
#include <hip/hip_runtime.h>
#include <hip/hip_fp16.h>
#include <cstdint>

#define NNODES 50000

__device__ inline void wave_lds_fence() {
  asm volatile("s_waitcnt lgkmcnt(0)" ::: "memory");
  __builtin_amdgcn_wave_barrier();
}

// ---------------- CSR build (dst-major, self-loops appended) ----------------
__global__ void hist_kernel(const int* __restrict__ ei, int E, int Nn, int* __restrict__ cnt) {
  int i = blockIdx.x * blockDim.x + threadIdx.x;
  int ET = E + Nn;
  if (i >= ET) return;
  int d = (i < E) ? ei[E + i] : (i - E);
  atomicAdd(&cnt[d], 1);
}

__global__ void scan1_kernel(const int* __restrict__ in, int n, int* __restrict__ incl,
                             int* __restrict__ bsum) {
  __shared__ int sd[256];
  int g = blockIdx.x * 256 + threadIdx.x;
  int v = (g < n) ? in[g] : 0;
  sd[threadIdx.x] = v;
  __syncthreads();
  for (int off = 1; off < 256; off <<= 1) {
    int t = (threadIdx.x >= off) ? sd[threadIdx.x - off] : 0;
    __syncthreads();
    sd[threadIdx.x] += t;
    __syncthreads();
  }
  if (g < n) incl[g] = sd[threadIdx.x];
  if (threadIdx.x == 255) bsum[blockIdx.x] = sd[255];
}

__global__ void scan3_kernel(const int* __restrict__ incl, const int* __restrict__ bscan,
                             int n, int* __restrict__ rowptr) {
  int g = blockIdx.x * 256 + threadIdx.x;
  if (g == 0) rowptr[0] = 0;
  if (g < n) {
    int off = (blockIdx.x > 0) ? bscan[blockIdx.x - 1] : 0;
    rowptr[g + 1] = incl[g] + off;
  }
}

__global__ void scatter_kernel(const int* __restrict__ ei, int E, int Nn,
                               const int* __restrict__ rowptr, int* __restrict__ cnt2,
                               int* __restrict__ esorted) {
  int i = blockIdx.x * blockDim.x + threadIdx.x;
  int ET = E + Nn;
  if (i >= ET) return;
  int s, d;
  if (i < E) { s = ei[i]; d = ei[E + i]; }
  else       { s = i - E; d = i - E; }
  int pos = rowptr[d] + atomicAdd(&cnt2[d], 1);
  esorted[pos] = s;
}

// ---------------- GEMM + fused attention logits (NT=32, register ping-pong W) --------------
// Hout[N,HCP](fp16, row stride HCP) = X[N,FIN](fp32) @ W[FIN,HC](fp32)
// R7's proven 8-deep register ping-pong (wb/wn), widened to NT=32 nodes per block
// with TM=8 rows per thread: per K-half the FMA:load ratio doubles (256 FMA-instr
// cover 8 in-flight dwordx4 loads) and block count halves, halving the per-wave
// W re-stream from L2 (L3: ~1.15 GB -> ~0.58 GB). No W in LDS (R8's 44.5 KB LDS
// tiling tanked occupancy to 28% and added 4.6M bank conflicts -> reverted).
// Logit reduction is ATOMIC-FREE (distinct LDS cells, R7-verified).
template <int FIN, int H, int C, int HCP, int BLOCK>
__global__ __launch_bounds__(BLOCK) void gemm_alpha_kernel(const float* __restrict__ X,
                                                           const float* __restrict__ W,
                                                           const float* __restrict__ a_s,
                                                           const float* __restrict__ a_d,
                                                           __half* __restrict__ Hout,
                                                           float* __restrict__ als8,
                                                           float* __restrict__ ald8,
                                                           int n_nodes) {
  constexpr int HC = H * C;
  constexpr int NT = 32;
  constexpr int TM = 8, TN = 4;
  constexpr int CG = HC / TN;
  constexpr int MAXC = C / TN;  // 4-col slices per head
  constexpr int PF = 8;         // W rows in flight per half
  static_assert(FIN % (2 * PF) == 0, "FIN must be a multiple of 16");
  __shared__ __align__(16) float xs[FIN * NT];  // [k][node]
  __shared__ float redS[NT][H][MAXC];
  __shared__ float redD[NT][H][MAXC];
  const int n0 = blockIdx.x * NT;
  const int nv = (n_nodes - n0 < NT) ? (n_nodes - n0) : NT;  // valid nodes this block

  // stage X block transposed into xs (rows >= nv zero-padded)
  for (int i = threadIdx.x * 4; i < NT * FIN; i += BLOCK * 4) {
    int node = i / FIN, k = i % FIN;
    float4 v = make_float4(0.f, 0.f, 0.f, 0.f);
    if (node < nv) v = *(const float4*)(X + (size_t)(n0 + node) * FIN + k);
    xs[(k + 0) * NT + node] = v.x;
    xs[(k + 1) * NT + node] = v.y;
    xs[(k + 2) * NT + node] = v.z;
    xs[(k + 3) * NT + node] = v.w;
  }
  __syncthreads();

  const int cg = threadIdx.x % CG;
  const int ng = threadIdx.x / CG;
  const bool compute = (ng < NT / TM);
  const int c0 = cg * TN;
  const int i0 = ng * TM;
  if (compute) {
    float acc[TM][TN];
#pragma unroll
    for (int i = 0; i < TM; ++i)
#pragma unroll
      for (int j = 0; j < TN; ++j) acc[i][j] = 0.f;
    const float* Wp = W + c0;
    float4 wb[PF], wn[PF];
#pragma unroll
    for (int j = 0; j < PF; ++j) wb[j] = *(const float4*)(Wp + (size_t)j * HC);
#pragma unroll 1
    for (int k0 = 0; k0 < FIN; k0 += 2 * PF) {
      // half A: prefetch rows k0+8..k0+15 into wn, consume wb (rows k0..k0+7)
#pragma unroll
      for (int j = 0; j < PF; ++j) wn[j] = *(const float4*)(Wp + (size_t)(k0 + PF + j) * HC);
#pragma unroll
      for (int j = 0; j < PF; ++j) {
        const float4 wv = wb[j];
        const float4 x0 = *(const float4*)(xs + (k0 + j) * NT + i0);
        const float4 x1 = *(const float4*)(xs + (k0 + j) * NT + i0 + 4);
        acc[0][0] += x0.x * wv.x; acc[0][1] += x0.x * wv.y; acc[0][2] += x0.x * wv.z; acc[0][3] += x0.x * wv.w;
        acc[1][0] += x0.y * wv.x; acc[1][1] += x0.y * wv.y; acc[1][2] += x0.y * wv.z; acc[1][3] += x0.y * wv.w;
        acc[2][0] += x0.z * wv.x; acc[2][1] += x0.z * wv.y; acc[2][2] += x0.z * wv.z; acc[2][3] += x0.z * wv.w;
        acc[3][0] += x0.w * wv.x; acc[3][1] += x0.w * wv.y; acc[3][2] += x0.w * wv.z; acc[3][3] += x0.w * wv.w;
        acc[4][0] += x1.x * wv.x; acc[4][1] += x1.x * wv.y; acc[4][2] += x1.x * wv.z; acc[4][3] += x1.x * wv.w;
        acc[5][0] += x1.y * wv.x; acc[5][1] += x1.y * wv.y; acc[5][2] += x1.y * wv.z; acc[5][3] += x1.y * wv.w;
        acc[6][0] += x1.z * wv.x; acc[6][1] += x1.z * wv.y; acc[6][2] += x1.z * wv.z; acc[6][3] += x1.z * wv.w;
        acc[7][0] += x1.w * wv.x; acc[7][1] += x1.w * wv.y; acc[7][2] += x1.w * wv.z; acc[7][3] += x1.w * wv.w;
      }
      // half B: prefetch next pair's first rows into wb, consume wn
      const int kp = (k0 + 2 * PF < FIN) ? (k0 + 2 * PF) : 0;  // last prefetch: dead value
#pragma unroll
      for (int j = 0; j < PF; ++j) wb[j] = *(const float4*)(Wp + (size_t)(kp + j) * HC);
#pragma unroll
      for (int j = 0; j < PF; ++j) {
        const float4 wv = wn[j];
        const float4 x0 = *(const float4*)(xs + (k0 + PF + j) * NT + i0);
        const float4 x1 = *(const float4*)(xs + (k0 + PF + j) * NT + i0 + 4);
        acc[0][0] += x0.x * wv.x; acc[0][1] += x0.x * wv.y; acc[0][2] += x0.x * wv.z; acc[0][3] += x0.x * wv.w;
        acc[1][0] += x0.y * wv.x; acc[1][1] += x0.y * wv.y; acc[1][2] += x0.y * wv.z; acc[1][3] += x0.y * wv.w;
        acc[2][0] += x0.z * wv.x; acc[2][1] += x0.z * wv.y; acc[2][2] += x0.z * wv.z; acc[2][3] += x0.z * wv.w;
        acc[3][0] += x0.w * wv.x; acc[3][1] += x0.w * wv.y; acc[3][2] += x0.w * wv.z; acc[3][3] += x0.w * wv.w;
        acc[4][0] += x1.x * wv.x; acc[4][1] += x1.x * wv.y; acc[4][2] += x1.x * wv.z; acc[4][3] += x1.x * wv.w;
        acc[5][0] += x1.y * wv.x; acc[5][1] += x1.y * wv.y; acc[5][2] += x1.y * wv.z; acc[5][3] += x1.y * wv.w;
        acc[6][0] += x1.z * wv.x; acc[6][1] += x1.z * wv.y; acc[6][2] += x1.z * wv.z; acc[6][3] += x1.z * wv.w;
        acc[7][0] += x1.w * wv.x; acc[7][1] += x1.w * wv.y; acc[7][2] += x1.w * wv.z; acc[7][3] += x1.w * wv.w;
      }
    }
    // store h (fp16, padded stride); rows beyond nv are skipped
#pragma unroll
    for (int i = 0; i < TM; ++i) {
      if (i0 + i < nv) {
        union { __half2 h2[2]; uint2 u; } pk;
        pk.h2[0] = __floats2half2_rn(acc[i][0], acc[i][1]);
        pk.h2[1] = __floats2half2_rn(acc[i][2], acc[i][3]);
        *(uint2*)(Hout + (size_t)(n0 + i0 + i) * HCP + c0) = pk.u;
      }
    }
    // logit partials: this thread's 4 cols all lie in head hd, slice cidx
    const int hd = c0 / C;
    const int cidx = (c0 % C) / TN;
    const float4 as4 = *(const float4*)(a_s + c0);
    const float4 ad4 = *(const float4*)(a_d + c0);
#pragma unroll
    for (int i = 0; i < TM; ++i) {
      float ps = acc[i][0] * as4.x + acc[i][1] * as4.y + acc[i][2] * as4.z + acc[i][3] * as4.w;
      float pd = acc[i][0] * ad4.x + acc[i][1] * ad4.y + acc[i][2] * ad4.z + acc[i][3] * ad4.w;
      redS[i0 + i][hd][cidx] = ps;
      redD[i0 + i][hd][cidx] = pd;
    }
  }
  __syncthreads();
  for (int z = threadIdx.x; z < NT * H; z += BLOCK) {
    int n = z / H, h = z % H;
    if (n < nv) {
      float ss = 0.f, dd = 0.f;
#pragma unroll
      for (int c = 0; c < MAXC; ++c) { ss += redS[n][h][c]; dd += redD[n][h][c]; }
      als8[(size_t)(n0 + n) * 8 + h] = ss;
      ald8[(size_t)(n0 + n) * 8 + h] = dd;
    }
  }
}

// ---------------- segment softmax + aggregate (one wave per dst node) ----------------
// No max-subtraction: scores are O(+-5) for this data scale, exp() is safe in fp32
// and alpha = exp(e)/sum exp(e) is mathematically identical to the max-shifted form.
//
// Gather layout: each lane owns one 16-B chunk (8 halves) of the src feature
// vector; 64 lanes = GROUPS edge-parallel groups x LPG chunk-lanes. Rows are
// HCP-padded so each per-edge gather covers exactly HCP*2/128 aligned lines.
template <int H, int C, int HCP, int RELU>
__global__ __launch_bounds__(256) void agg_kernel(const __half* __restrict__ Hbuf,
                                                  const float* __restrict__ als8,
                                                  const float* __restrict__ ald8,
                                                  const int* __restrict__ rowptr,
                                                  const int* __restrict__ esrc,
                                                  const float* __restrict__ bias,
                                                  float* __restrict__ Out, int n_nodes) {
  constexpr int HC = H * C;
  constexpr int NCHUNK = HC / 8;                    // real 16-B chunks per feature vector
  constexpr int GROUPS = (NCHUNK <= 16) ? 4 : 2;    // edge-parallel groups per wave
  constexpr int LPG = 64 / GROUPS;                  // chunk-lanes per group
  constexpr int UN = 3;                             // edges in flight per group (MLP)
  constexpr int TPAD = 72;                          // 64 staged + group-stride overshoot pad
  const int wave = threadIdx.x >> 6;
  const int lane = threadIdx.x & 63;
  const int grp = lane / LPG;
  const int lg = lane % LPG;
  const int n = blockIdx.x * 4 + wave;
  __shared__ float s_w[4][TPAD * H];  // per-edge softmax weights for current chunk
  __shared__ int s_src[4][TPAD];
  if (n >= n_nodes) return;

  // zero the overshoot pad once (weight 0 => padded slots contribute nothing)
  if (lane < TPAD - 64) s_src[wave][64 + lane] = 0;
  for (int z = lane; z < (TPAD - 64) * H; z += 64) s_w[wave][64 * H + z] = 0.f;

  const int e0 = rowptr[n];
  const int e1 = rowptr[n + 1];

  float aldn[H];
#pragma unroll
  for (int h = 0; h < H; ++h) aldn[h] = ald8[n * 8 + h];

  // lane's chunk lies in exactly one head since C % 8 == 0 (C = 16 or 40)
  const int head = min((lg * 8) / C, H - 1);
  const bool act = lg < NCHUNK;

  float acc[8];
  float lsum = 0.f;
#pragma unroll
  for (int j = 0; j < 8; ++j) acc[j] = 0.f;

  for (int base = e0; base < e1; base += 64) {
    const int cnt = (e1 - base < 64) ? (e1 - base) : 64;
    int sreg = 0;
    if (lane < cnt) sreg = esrc[base + lane];
    s_src[wave][lane] = sreg;  // lanes >= cnt stage src 0 with weight 0 (harmless pad)
    if (lane < cnt) {
      const float4 qa = *(const float4*)(als8 + (size_t)sreg * 8);
      const float4 qb = *(const float4*)(als8 + (size_t)sreg * 8 + 4);
      const float q[8] = {qa.x, qa.y, qa.z, qa.w, qb.x, qb.y, qb.z, qb.w};
#pragma unroll
      for (int h = 0; h < H; ++h) {
        float v = q[h] + aldn[h];
        v = v > 0.f ? v : 0.2f * v;  // leaky_relu 0.2
        s_w[wave][lane * H + h] = __expf(v);
      }
    } else {
#pragma unroll
      for (int h = 0; h < H; ++h) s_w[wave][lane * H + h] = 0.f;
    }
    wave_lds_fence();
    // each group sweeps edges t = grp, grp+GROUPS, ...; UN edges per group in flight
    const int nit = (cnt + GROUPS - 1) / GROUPS;
    for (int i = 0; i < nit; i += UN) {
      int tt[UN], si[UN];
      uint4 v[UN];
      float w[UN];
#pragma unroll
      for (int k = 0; k < UN; ++k) tt[k] = (i + k) * GROUPS + grp;
#pragma unroll
      for (int k = 0; k < UN; ++k) si[k] = s_src[wave][tt[k]];
#pragma unroll
      for (int k = 0; k < UN; ++k)
        if (act) v[k] = *(const uint4*)(Hbuf + (size_t)si[k] * HCP + lg * 8);
#pragma unroll
      for (int k = 0; k < UN; ++k) w[k] = s_w[wave][tt[k] * H + head];
#pragma unroll
      for (int k = 0; k < UN; ++k)
        if (act) {
          const __half2* hp = (const __half2*)&v[k];
          float2 f0 = __half22float2(hp[0]);
          float2 f1 = __half22float2(hp[1]);
          float2 f2 = __half22float2(hp[2]);
          float2 f3 = __half22float2(hp[3]);
          lsum += w[k];
          acc[0] += w[k] * f0.x; acc[1] += w[k] * f0.y;
          acc[2] += w[k] * f1.x; acc[3] += w[k] * f1.y;
          acc[4] += w[k] * f2.x; acc[5] += w[k] * f2.y;
          acc[6] += w[k] * f3.x; acc[7] += w[k] * f3.y;
        }
    }
    wave_lds_fence();
  }

  // fold group partials: lanes with equal lg hold the same channels
#pragma unroll
  for (int off = LPG; off < 64; off <<= 1) {
    lsum += __shfl_xor(lsum, off);
#pragma unroll
    for (int j = 0; j < 8; ++j) acc[j] += __shfl_xor(acc[j], off);
  }

  if (grp == 0 && act) {
    const float inv = 1.f / lsum;
    const float4 b0 = *(const float4*)(bias + lg * 8);
    const float4 b1 = *(const float4*)(bias + lg * 8 + 4);
    float4 o0, o1;
    o0.x = acc[0] * inv + b0.x; o0.y = acc[1] * inv + b0.y;
    o0.z = acc[2] * inv + b0.z; o0.w = acc[3] * inv + b0.w;
    o1.x = acc[4] * inv + b1.x; o1.y = acc[5] * inv + b1.y;
    o1.z = acc[6] * inv + b1.z; o1.w = acc[7] * inv + b1.w;
    if (RELU) {
      o0.x = fmaxf(o0.x, 0.f); o0.y = fmaxf(o0.y, 0.f);
      o0.z = fmaxf(o0.z, 0.f); o0.w = fmaxf(o0.w, 0.f);
      o1.x = fmaxf(o1.x, 0.f); o1.y = fmaxf(o1.y, 0.f);
      o1.z = fmaxf(o1.z, 0.f); o1.w = fmaxf(o1.w, 0.f);
    }
    *(float4*)(Out + (size_t)n * HC + lg * 8) = o0;
    *(float4*)(Out + (size_t)n * HC + lg * 8 + 4) = o1;
  }
}

// ---------------- launch ----------------
extern "C" void kernel_launch(void* const* d_in, const int* in_sizes, int n_in,
                              void* d_out, int out_size, void* d_ws, size_t ws_size,
                              hipStream_t stream) {
  const int N = NNODES;
  const float* x  = (const float*)d_in[0];
  const int* ei   = (const int*)d_in[1];
  const float* W1 = (const float*)d_in[2];
  const float* as1 = (const float*)d_in[3];
  const float* ad1 = (const float*)d_in[4];
  const float* b1  = (const float*)d_in[5];
  const float* W2  = (const float*)d_in[6];
  const float* as2 = (const float*)d_in[7];
  const float* ad2 = (const float*)d_in[8];
  const float* b2  = (const float*)d_in[9];
  const float* W3  = (const float*)d_in[10];
  const float* as3 = (const float*)d_in[11];
  const float* ad3 = (const float*)d_in[12];
  const float* b3  = (const float*)d_in[13];
  float* out = (float*)d_out;
  const int E = in_sizes[1] / 2;
  const int ET = E + N;

  char* ws = (char*)d_ws;
  size_t off = 0;
  auto alloc = [&](size_t bytes) -> char* {
    char* p = ws + off;
    off += (bytes + 255) & ~(size_t)255;
    return p;
  };
  int* cnt     = (int*)alloc((size_t)N * 4);
  int* cnt2    = (int*)alloc((size_t)N * 4);
  int* incl    = (int*)alloc((size_t)N * 4);
  int* bsum    = (int*)alloc(512 * 4);
  int* bscan   = (int*)alloc(256 * 4);
  int* rowptr  = (int*)alloc((size_t)(N + 1) * 4);
  int* esorted = (int*)alloc((size_t)ET * 4);
  float* als   = (float*)alloc((size_t)N * 8 * 4);
  float* ald   = (float*)alloc((size_t)N * 8 * 4);
  __half* hbuf = (__half*)alloc((size_t)N * 256 * 2);  // max padded row stride = 256 halves
  float* abuf  = (float*)alloc((size_t)N * 112 * 4);

  hipMemsetAsync(cnt, 0, (size_t)N * 4, stream);
  hipMemsetAsync(cnt2, 0, (size_t)N * 4, stream);

  const int B1 = (N + 255) / 256;
  hist_kernel<<<(ET + 255) / 256, 256, 0, stream>>>(ei, E, N, cnt);
  scan1_kernel<<<B1, 256, 0, stream>>>(cnt, N, incl, bsum);
  scan1_kernel<<<1, 256, 0, stream>>>(bsum, B1, bscan, bsum + 256);
  scan3_kernel<<<B1, 256, 0, stream>>>(incl, bscan, N, rowptr);
  scatter_kernel<<<(ET + 255) / 256, 256, 0, stream>>>(ei, E, N, rowptr, cnt2, esorted);

  const int GB = (N + 31) / 32;  // 1563 blocks, 32 nodes each (tail block: 16)

  // Layer 1: 128 -> 7x16, rows padded 112 -> 128 halves (256 B = 2 aligned lines/gather)
  gemm_alpha_kernel<128, 7, 16, 128, 128><<<GB, 128, 0, stream>>>(x, W1, as1, ad1, hbuf, als, ald, N);
  agg_kernel<7, 16, 128, 1><<<(N + 3) / 4, 256, 0, stream>>>(hbuf, als, ald, rowptr, esorted, b1, abuf, N);
  // Layer 2: 112 -> 6x16, stride 96 halves (192 B) already always 2 lines -> unpadded
  gemm_alpha_kernel<112, 6, 16, 96, 128><<<GB, 128, 0, stream>>>(abuf, W2, as2, ad2, hbuf, als, ald, N);
  agg_kernel<6, 16, 96, 1><<<(N + 3) / 4, 256, 0, stream>>>(hbuf, als, ald, rowptr, esorted, b2, abuf, N);
  // Layer 3: 96 -> 6x40 (no relu), rows padded 240 -> 256 halves (512 B = 4 aligned lines)
  gemm_alpha_kernel<96, 6, 40, 256, 256><<<GB, 256, 0, stream>>>(abuf, W3, as3, ad3, hbuf, als, ald, N);
  agg_kernel<6, 40, 256, 0><<<(N + 3) / 4, 256, 0, stream>>>(hbuf, als, ald, rowptr, esorted, b3, out, N);
}